// Round 6
// baseline (3171.865 us; speedup 1.0000x reference)
//
#include <hip/hip_runtime.h>
#include <hip/hip_fp16.h>

// ---------------------------------------------------------------------------
// GCN 3-layer forward:  (GCNConv -> BN) x2 -> GCNConv
// N=100000, E=1600000, IN=H=128, OUT=64
// Round 5: bucket-sorted edges (128-node buckets, XCD-segmented scatter of
//          packed (src<<7|dstLow) words -> kills CSR write amplification) +
//          LDS-atomic bucket gather (no esrc/row_ptr at all).
// ---------------------------------------------------------------------------

constexpr int BSH = 7;            // 128 nodes per bucket
constexpr int NXCD = 8;

static __device__ inline ushort f2h(float f) {
    union { __half h; ushort u; } cv;
    cv.h = __float2half_rn(f);
    return cv.u;
}
static __device__ inline float2 h2f2(unsigned int u) {
    union { unsigned int u; __half2 h; } cv;
    cv.u = u;
    return __half22float2(cv.h);
}

// 8 LDS float atomic adds from one uint4 of 8 f16
#define LDSACC8(arow, v) do { float2 _f; \
    _f = h2f2((v).x); atomicAdd(&(arow)[0], _f.x); atomicAdd(&(arow)[1], _f.y); \
    _f = h2f2((v).y); atomicAdd(&(arow)[2], _f.x); atomicAdd(&(arow)[3], _f.y); \
    _f = h2f2((v).z); atomicAdd(&(arow)[4], _f.x); atomicAdd(&(arow)[5], _f.y); \
    _f = h2f2((v).w); atomicAdd(&(arow)[6], _f.x); atomicAdd(&(arow)[7], _f.y); \
} while (0)

// ---- phase A: per-xcd bucket histogram + per-node degree ------------------
__global__ __launch_bounds__(256) void count_k(const int* __restrict__ dst,
                                               int* __restrict__ hist,
                                               int* __restrict__ deg,
                                               int E, int EPB, int nbuk) {
    __shared__ int lh[1024];
    for (int i = threadIdx.x; i < nbuk; i += 256) lh[i] = 0;
    __syncthreads();
    const int e0 = blockIdx.x * EPB;
    const int e1 = min(e0 + EPB, E);
    for (int e = e0 + threadIdx.x; e < e1; e += 256) {
        int d = dst[e];
        atomicAdd(&lh[d >> BSH], 1);
        atomicAdd(&deg[d], 1);
    }
    __syncthreads();
    const int xcd = blockIdx.x & (NXCD - 1);
    for (int i = threadIdx.x; i < nbuk; i += 256) {
        int v = lh[i];
        if (v) atomicAdd(&hist[xcd * nbuk + i], v);
    }
}

__global__ void deg_to_dis_k(const int* __restrict__ deg, float* __restrict__ dis, int n) {
    int i = blockIdx.x * blockDim.x + threadIdx.x;
    if (i < n) dis[i] = rsqrtf((float)deg[i] + 1.0f);   // +1 self loop
}

// ---- phase B: scan hist (key order: bucket-major, xcd-minor) --------------
__global__ __launch_bounds__(256) void scan_hist_k(const int* __restrict__ hist,
                                                   int* __restrict__ cur,
                                                   int* __restrict__ bstart,
                                                   int nbuk, int E) {
    const int NT = nbuk * NXCD;          // <= 8192 assumed
    const int C = (NT + 255) / 256;      // <= 32
    int vals[32];
    const int tid = threadIdx.x;
    int sum = 0;
#pragma unroll
    for (int k = 0; k < 32; ++k) {
        if (k >= C) break;
        int key = tid * C + k;
        int v = 0;
        if (key < NT) {
            int b = key >> 3, x = key & 7;
            v = hist[x * nbuk + b];
        }
        vals[k] = v;
        sum += v;
    }
    __shared__ int part[256];
    part[tid] = sum;
    __syncthreads();
    for (int off = 1; off < 256; off <<= 1) {
        int t = 0;
        if (tid >= off) t = part[tid - off];
        __syncthreads();
        part[tid] += t;
        __syncthreads();
    }
    int run = (tid == 0) ? 0 : part[tid - 1];
#pragma unroll
    for (int k = 0; k < 32; ++k) {
        if (k >= C) break;
        int key = tid * C + k;
        if (key < NT) {
            int b = key >> 3, x = key & 7;
            cur[x * nbuk + b] = run;
            if (x == 0) bstart[b] = run;
        }
        run += vals[k];
    }
    if (tid == 0) bstart[nbuk] = E;
}

// ---- phase C: scatter packed edges into (bucket, xcd) segments ------------
__global__ __launch_bounds__(256) void scatter_bucket_k(const int* __restrict__ src,
                                                        const int* __restrict__ dst,
                                                        int* __restrict__ cur,
                                                        unsigned int* __restrict__ ebuf,
                                                        int E, int EPB, int nbuk) {
    const int e0 = blockIdx.x * EPB;
    const int e1 = min(e0 + EPB, E);
    const int xcd = blockIdx.x & (NXCD - 1);
    for (int e = e0 + threadIdx.x; e < e1; e += 256) {
        int d = dst[e];
        int s = src[e];
        int b = d >> BSH;
        int pos = atomicAdd(&cur[xcd * nbuk + b], 1);
        ebuf[pos] = ((unsigned int)s << BSH) | (unsigned int)(d & 127);
    }
}

// ------- GEMM: Hs = f16( (BN(X) @ W) * dis ), chunk-major output ----------
// Hs layout: [NCHUNK][N][32 f16], chunk c holds columns [32c, 32c+32).
template <int OUTD, bool BNIN>
__global__ __launch_bounds__(256) void gemm_k(const float* __restrict__ X,
                                              const float* __restrict__ W,
                                              const float* __restrict__ scale,
                                              const float* __restrict__ shift,
                                              const float* __restrict__ dis,
                                              ushort* __restrict__ Hs, int n) {
    constexpr int K = 128;
    constexpr int ROWS = 32;
    constexpr int CQ = OUTD / 4;      // col quads per row: 32 or 16
    constexpr int TR = 256 / CQ;      // thread groups along rows: 8 or 16
    constexpr int RPT = ROWS / TR;    // rows per thread: 4 or 2

    __shared__ float ws[K * OUTD];
    __shared__ float xs[ROWS][K];

    const int tx = threadIdx.x;

    // stage W
    {
        const float4* W4 = (const float4*)W;
        float4* ws4 = (float4*)ws;
        constexpr int tot = K * OUTD / 4;
        for (int i = tx; i < tot; i += 256) ws4[i] = W4[i];
    }
    // stage X tile (ROWS x K), BN applied on the fly
    const int row0 = blockIdx.x * ROWS;
    {
        const float4* X4 = (const float4*)X;
        constexpr int tot = ROWS * K / 4;  // 1024
        for (int i = tx; i < tot; i += 256) {
            int r = i / (K / 4);
            int kk = i - r * (K / 4);
            int gr = row0 + r;
            float4 v = make_float4(0.f, 0.f, 0.f, 0.f);
            if (gr < n) {
                v = X4[(size_t)gr * (K / 4) + kk];
                if (BNIN) {
                    float4 sc = ((const float4*)scale)[kk];
                    float4 sh = ((const float4*)shift)[kk];
                    v.x = v.x * sc.x + sh.x;
                    v.y = v.y * sc.y + sh.y;
                    v.z = v.z * sc.z + sh.z;
                    v.w = v.w * sc.w + sh.w;
                }
            }
            ((float4*)&xs[r][0])[kk] = v;
        }
    }
    __syncthreads();

    const int cq = tx % CQ;
    const int tr = tx / CQ;

    float acc[RPT][4];
#pragma unroll
    for (int r = 0; r < RPT; ++r)
#pragma unroll
        for (int c = 0; c < 4; ++c) acc[r][c] = 0.f;

#pragma unroll 8
    for (int k = 0; k < K; ++k) {
        float4 wv = ((const float4*)(&ws[k * OUTD]))[cq];
#pragma unroll
        for (int r = 0; r < RPT; ++r) {
            float xv = xs[tr * RPT + r][k];
            acc[r][0] += xv * wv.x;
            acc[r][1] += xv * wv.y;
            acc[r][2] += xv * wv.z;
            acc[r][3] += xv * wv.w;
        }
    }

    const int c = cq >> 3;          // 32-col chunk index
    const int qin = cq & 7;         // quad within chunk
#pragma unroll
    for (int r = 0; r < RPT; ++r) {
        int gr = row0 + tr * RPT + r;
        if (gr < n) {
            float dd = dis[gr];
            ushort4 pk;
            pk.x = f2h(acc[r][0] * dd);
            pk.y = f2h(acc[r][1] * dd);
            pk.z = f2h(acc[r][2] * dd);
            pk.w = f2h(acc[r][3] * dd);
            ((ushort4*)Hs)[((size_t)c * n + gr) * 8 + qin] = pk;
        }
    }
}

// ---------------- bucket gather: LDS accumulation (+ fused BN stats) -------
// block = (bucket, chunk). accum[128 nodes][33 f32] in LDS (pad kills bank
// conflicts of stride-32 rows). Edges are packed (src<<7 | dstLow).
template <int OUTD, bool STATS>
__global__ __launch_bounds__(256) void gather_bucket_k(
        const ushort* __restrict__ Hs, const float* __restrict__ dis,
        const float* __restrict__ bias, const unsigned int* __restrict__ ebuf,
        const int* __restrict__ bstart, float* __restrict__ O,
        float* __restrict__ sums, float* __restrict__ sumsq, int n) {
    constexpr int NCHUNK = OUTD / 32;   // 4 or 2

    __shared__ float accsm[128 * 33];
    __shared__ float s_sum[32];
    __shared__ float s_sq[32];

    const int chunk  = blockIdx.x & (NCHUNK - 1);
    const int bucket = blockIdx.x / NCHUNK;
    const int node0  = bucket << BSH;

    for (int i = threadIdx.x; i < 128 * 33; i += 256) accsm[i] = 0.f;
    if (STATS && threadIdx.x < 32) { s_sum[threadIdx.x] = 0.f; s_sq[threadIdx.x] = 0.f; }
    __syncthreads();

    const uint4* Hc = (const uint4*)Hs + (size_t)chunk * n * 4;   // 4 uint4/row
    const int pair = threadIdx.x >> 1;
    const int hoff = (threadIdx.x & 1) * 2;    // uint4 offset in row
    const int coff = (threadIdx.x & 1) * 16;   // col offset in accum row

    const int beg = bstart[bucket];
    const int end = bstart[bucket + 1];

    int base = beg;
    for (; base + 512 <= end; base += 512) {
        unsigned int p0 = ebuf[base + pair];
        unsigned int p1 = ebuf[base + 128 + pair];
        unsigned int p2 = ebuf[base + 256 + pair];
        unsigned int p3 = ebuf[base + 384 + pair];
        uint4 a0 = Hc[(size_t)(p0 >> BSH) * 4 + hoff];
        uint4 b0 = Hc[(size_t)(p0 >> BSH) * 4 + hoff + 1];
        uint4 a1 = Hc[(size_t)(p1 >> BSH) * 4 + hoff];
        uint4 b1 = Hc[(size_t)(p1 >> BSH) * 4 + hoff + 1];
        uint4 a2 = Hc[(size_t)(p2 >> BSH) * 4 + hoff];
        uint4 b2 = Hc[(size_t)(p2 >> BSH) * 4 + hoff + 1];
        uint4 a3 = Hc[(size_t)(p3 >> BSH) * 4 + hoff];
        uint4 b3 = Hc[(size_t)(p3 >> BSH) * 4 + hoff + 1];
        float* r0 = &accsm[(int)(p0 & 127) * 33 + coff];
        float* r1 = &accsm[(int)(p1 & 127) * 33 + coff];
        float* r2 = &accsm[(int)(p2 & 127) * 33 + coff];
        float* r3 = &accsm[(int)(p3 & 127) * 33 + coff];
        LDSACC8(r0, a0); LDSACC8(r0 + 8, b0);
        LDSACC8(r1, a1); LDSACC8(r1 + 8, b1);
        LDSACC8(r2, a2); LDSACC8(r2 + 8, b2);
        LDSACC8(r3, a3); LDSACC8(r3 + 8, b3);
    }
    for (; base < end; base += 128) {
        int idx = base + pair;
        if (idx < end) {
            unsigned int p = ebuf[idx];
            uint4 a = Hc[(size_t)(p >> BSH) * 4 + hoff];
            uint4 bb = Hc[(size_t)(p >> BSH) * 4 + hoff + 1];
            float* r = &accsm[(int)(p & 127) * 33 + coff];
            LDSACC8(r, a); LDSACC8(r + 8, bb);
        }
    }
    __syncthreads();

    float o[16];
#pragma unroll
    for (int k = 0; k < 16; ++k) o[k] = 0.f;

    const int dl = pair;
    const int node = node0 + dl;
    if (node < n) {
        uint4 v0 = Hc[(size_t)node * 4 + hoff];
        uint4 v1 = Hc[(size_t)node * 4 + hoff + 1];
        const float* arow = &accsm[dl * 33 + coff];
        float2 f;
        f = h2f2(v0.x); o[0]  = arow[0]  + f.x; o[1]  = arow[1]  + f.y;
        f = h2f2(v0.y); o[2]  = arow[2]  + f.x; o[3]  = arow[3]  + f.y;
        f = h2f2(v0.z); o[4]  = arow[4]  + f.x; o[5]  = arow[5]  + f.y;
        f = h2f2(v0.w); o[6]  = arow[6]  + f.x; o[7]  = arow[7]  + f.y;
        f = h2f2(v1.x); o[8]  = arow[8]  + f.x; o[9]  = arow[9]  + f.y;
        f = h2f2(v1.y); o[10] = arow[10] + f.x; o[11] = arow[11] + f.y;
        f = h2f2(v1.z); o[12] = arow[12] + f.x; o[13] = arow[13] + f.y;
        f = h2f2(v1.w); o[14] = arow[14] + f.x; o[15] = arow[15] + f.y;

        float dd = dis[node];
        const float4* B4 = (const float4*)bias + chunk * 8 + (coff >> 2);
        float4 q0 = B4[0], q1 = B4[1], q2 = B4[2], q3 = B4[3];
        o[0]  = o[0]  * dd + q0.x;
        o[1]  = o[1]  * dd + q0.y;
        o[2]  = o[2]  * dd + q0.z;
        o[3]  = o[3]  * dd + q0.w;
        o[4]  = o[4]  * dd + q1.x;
        o[5]  = o[5]  * dd + q1.y;
        o[6]  = o[6]  * dd + q1.z;
        o[7]  = o[7]  * dd + q1.w;
        o[8]  = o[8]  * dd + q2.x;
        o[9]  = o[9]  * dd + q2.y;
        o[10] = o[10] * dd + q2.z;
        o[11] = o[11] * dd + q2.w;
        o[12] = o[12] * dd + q3.x;
        o[13] = o[13] * dd + q3.y;
        o[14] = o[14] * dd + q3.z;
        o[15] = o[15] * dd + q3.w;

        float4* O4 = (float4*)O + (size_t)node * (OUTD / 4) + chunk * 8 + (coff >> 2);
        O4[0] = make_float4(o[0], o[1], o[2], o[3]);
        O4[1] = make_float4(o[4], o[5], o[6], o[7]);
        O4[2] = make_float4(o[8], o[9], o[10], o[11]);
        O4[3] = make_float4(o[12], o[13], o[14], o[15]);
    }

    if (STATS) {
        // lanes of equal parity hold the same 16 cols for 32 different nodes
        float sv[16], qv[16];
#pragma unroll
        for (int k = 0; k < 16; ++k) { sv[k] = o[k]; qv[k] = o[k] * o[k]; }
#pragma unroll
        for (int k = 0; k < 16; ++k) {
#pragma unroll
            for (int m = 2; m <= 32; m <<= 1) {
                sv[k] += __shfl_xor(sv[k], m);
                qv[k] += __shfl_xor(qv[k], m);
            }
        }
        if ((threadIdx.x & 63) < 2) {
#pragma unroll
            for (int k = 0; k < 16; ++k) {
                atomicAdd(&s_sum[coff + k], sv[k]);
                atomicAdd(&s_sq[coff + k], qv[k]);
            }
        }
        __syncthreads();
        if (threadIdx.x < 32) {
            atomicAdd(&sums[chunk * 32 + threadIdx.x], s_sum[threadIdx.x]);
            atomicAdd(&sumsq[chunk * 32 + threadIdx.x], s_sq[threadIdx.x]);
        }
    }
}

// ---------------- BN finalize: scale/shift from sums ----------------------
__global__ void bn_finalize_k(const float* __restrict__ sums, const float* __restrict__ sumsq,
                              const float* __restrict__ g, const float* __restrict__ be,
                              float* __restrict__ scale, float* __restrict__ shift, int n) {
    int c = threadIdx.x;  // 128 threads
    float inv_n = 1.0f / (float)n;
    float m = sums[c] * inv_n;
    float v = sumsq[c] * inv_n - m * m;
    float sc = rsqrtf(v + 1e-5f) * g[c];
    scale[c] = sc;
    shift[c] = be[c] - m * sc;
}

// ---------------------------------------------------------------------------
extern "C" void kernel_launch(void* const* d_in, const int* in_sizes, int n_in,
                              void* d_out, int out_size, void* d_ws, size_t ws_size,
                              hipStream_t stream) {
    const float* x   = (const float*)d_in[0];
    const int*   ei  = (const int*)d_in[1];
    const float* W1  = (const float*)d_in[2];
    const float* b1  = (const float*)d_in[3];
    const float* g1  = (const float*)d_in[4];
    const float* be1 = (const float*)d_in[5];
    const float* W2  = (const float*)d_in[6];
    const float* b2  = (const float*)d_in[7];
    const float* g2  = (const float*)d_in[8];
    const float* be2 = (const float*)d_in[9];
    const float* W3  = (const float*)d_in[10];
    const float* b3  = (const float*)d_in[11];
    float* out = (float*)d_out;

    const int N = in_sizes[0] / 128;
    const int E = in_sizes[1] / 2;
    const int* src = ei;
    const int* dst = ei + E;
    const int NBUK = (N + 127) >> BSH;

    // ---- workspace layout ----
    float* wsp   = (float*)d_ws;
    float* dis   = wsp;                               // N f32
    float* stats = wsp + N;                           // 512 f32
    int*   meta  = (int*)(stats + 512);               // hist | cur | bstart
    int*   hist   = meta;                             // NBUK*8
    int*   cur    = hist + NBUK * NXCD;               // NBUK*8
    int*   bstart = cur + NBUK * NXCD;                // NBUK+1
    float* bufA  = (float*)(bstart + NBUK + 1 + 64);  // N*128 f32 region (Hs f16)
    float* bufB  = bufA + (size_t)N * 128;            // N*128 f32 (agg out)
    unsigned int* ebuf = (unsigned int*)(bufB + (size_t)N * 128);  // E u32

    ushort* Hs = (ushort*)bufA;                       // [NCHUNK][N][32] f16
    int* deg = (int*)bufA;                            // N ints (pre-GEMM only)

    float* sums  = stats;
    float* sumsq = stats + 128;
    float* scale = stats + 256;
    float* shift = stats + 384;

    const int BS = 256;
    dim3 blk(BS);
    const int NB = (N + 255) / 256;
    const int SGRID = 512;                 // count/scatter blocks (multiple of 8)
    const int EPB = (E + SGRID - 1) / SGRID;

    // ---- bucket sort build ----
    hipMemsetAsync(deg, 0, (size_t)N * 4, stream);
    hipMemsetAsync(hist, 0, (size_t)NBUK * NXCD * 4, stream);
    count_k<<<dim3(SGRID), blk, 0, stream>>>(dst, hist, deg, E, EPB, NBUK);
    deg_to_dis_k<<<dim3(NB), blk, 0, stream>>>(deg, dis, N);
    scan_hist_k<<<dim3(1), blk, 0, stream>>>(hist, cur, bstart, NBUK, E);
    scatter_bucket_k<<<dim3(SGRID), blk, 0, stream>>>(src, dst, cur, ebuf, E, EPB, NBUK);

    const int gemm_grid = (N + 31) / 32;

    // ---- layer 1 ----
    gemm_k<128, false><<<dim3(gemm_grid), blk, 0, stream>>>(x, W1, nullptr, nullptr, dis, Hs, N);
    hipMemsetAsync(stats, 0, 256 * 4, stream);
    gather_bucket_k<128, true><<<dim3(NBUK * 4), blk, 0, stream>>>(Hs, dis, b1, ebuf, bstart,
                                                                   bufB, sums, sumsq, N);
    bn_finalize_k<<<dim3(1), dim3(128), 0, stream>>>(sums, sumsq, g1, be1, scale, shift, N);

    // ---- layer 2 (BN applied inside GEMM staging) ----
    gemm_k<128, true><<<dim3(gemm_grid), blk, 0, stream>>>(bufB, W2, scale, shift, dis, Hs, N);
    hipMemsetAsync(stats, 0, 256 * 4, stream);
    gather_bucket_k<128, true><<<dim3(NBUK * 4), blk, 0, stream>>>(Hs, dis, b2, ebuf, bstart,
                                                                   bufB, sums, sumsq, N);
    bn_finalize_k<<<dim3(1), dim3(128), 0, stream>>>(sums, sumsq, g2, be2, scale, shift, N);

    // ---- layer 3 (OUT = 64, straight to d_out) ----
    gemm_k<64, true><<<dim3(gemm_grid), blk, 0, stream>>>(bufB, W3, scale, shift, dis, Hs, N);
    gather_bucket_k<64, false><<<dim3(NBUK * 2), blk, 0, stream>>>(Hs, dis, b3, ebuf, bstart,
                                                                   out, nullptr, nullptr, N);
}

// Round 7
// 682.931 us; speedup vs baseline: 4.6445x; 4.6445x over previous
//
#include <hip/hip_runtime.h>
#include <hip/hip_fp16.h>

// ---------------------------------------------------------------------------
// GCN 3-layer forward:  (GCNConv -> BN) x2 -> GCNConv
// N=100000, E=1600000, IN=H=128, OUT=64
// Round 6: round-4 register gather (proven) + bucket-sorted CSR build
//          (packed XCD-segmented scatter + per-bucket LDS counting sort)
//          replacing the write-amplified edge_scatter.
// ---------------------------------------------------------------------------

constexpr int BSH = 7;            // 128 nodes per bucket
constexpr int NXCD = 8;

static __device__ inline ushort f2h(float f) {
    union { __half h; ushort u; } cv;
    cv.h = __float2half_rn(f);
    return cv.u;
}
static __device__ inline float2 h2f2(unsigned int u) {
    union { unsigned int u; __half2 h; } cv;
    cv.u = u;
    return __half22float2(cv.h);
}

#define ACC8(base, v) do { float2 _f; \
    _f = h2f2((v).x); acc[(base)+0] += _f.x; acc[(base)+1] += _f.y; \
    _f = h2f2((v).y); acc[(base)+2] += _f.x; acc[(base)+3] += _f.y; \
    _f = h2f2((v).z); acc[(base)+4] += _f.x; acc[(base)+5] += _f.y; \
    _f = h2f2((v).w); acc[(base)+6] += _f.x; acc[(base)+7] += _f.y; \
} while (0)

// ---- phase A: per-xcd bucket histogram + per-node degree ------------------
__global__ __launch_bounds__(256) void count_k(const int* __restrict__ dst,
                                               int* __restrict__ hist,
                                               int* __restrict__ deg,
                                               int E, int EPB, int nbuk) {
    __shared__ int lh[1024];
    for (int i = threadIdx.x; i < nbuk; i += 256) lh[i] = 0;
    __syncthreads();
    const int e0 = blockIdx.x * EPB;
    const int e1 = min(e0 + EPB, E);
    for (int e = e0 + threadIdx.x; e < e1; e += 256) {
        int d = dst[e];
        atomicAdd(&lh[d >> BSH], 1);
        atomicAdd(&deg[d], 1);
    }
    __syncthreads();
    const int xcd = blockIdx.x & (NXCD - 1);
    for (int i = threadIdx.x; i < nbuk; i += 256) {
        int v = lh[i];
        if (v) atomicAdd(&hist[xcd * nbuk + i], v);
    }
}

__global__ void deg_to_dis_k(const int* __restrict__ deg, float* __restrict__ dis, int n) {
    int i = blockIdx.x * blockDim.x + threadIdx.x;
    if (i < n) dis[i] = rsqrtf((float)deg[i] + 1.0f);   // +1 self loop
}

// ---- phase B: scan hist (key order: bucket-major, xcd-minor) --------------
__global__ __launch_bounds__(256) void scan_hist_k(const int* __restrict__ hist,
                                                   int* __restrict__ cur,
                                                   int* __restrict__ bstart,
                                                   int* __restrict__ row_ptr,
                                                   int nbuk, int n, int E) {
    const int NT = nbuk * NXCD;          // <= 8192 assumed
    const int C = (NT + 255) / 256;      // <= 32
    int vals[32];
    const int tid = threadIdx.x;
    int sum = 0;
#pragma unroll
    for (int k = 0; k < 32; ++k) {
        if (k >= C) break;
        int key = tid * C + k;
        int v = 0;
        if (key < NT) {
            int b = key >> 3, x = key & 7;
            v = hist[x * nbuk + b];
        }
        vals[k] = v;
        sum += v;
    }
    __shared__ int part[256];
    part[tid] = sum;
    __syncthreads();
    for (int off = 1; off < 256; off <<= 1) {
        int t = 0;
        if (tid >= off) t = part[tid - off];
        __syncthreads();
        part[tid] += t;
        __syncthreads();
    }
    int run = (tid == 0) ? 0 : part[tid - 1];
#pragma unroll
    for (int k = 0; k < 32; ++k) {
        if (k >= C) break;
        int key = tid * C + k;
        if (key < NT) {
            int b = key >> 3, x = key & 7;
            cur[x * nbuk + b] = run;
            if (x == 0) bstart[b] = run;
        }
        run += vals[k];
    }
    if (tid == 0) { bstart[nbuk] = E; row_ptr[n] = E; }
}

// ---- phase C: scatter packed edges into (bucket, xcd) segments ------------
__global__ __launch_bounds__(256) void scatter_bucket_k(const int* __restrict__ src,
                                                        const int* __restrict__ dst,
                                                        int* __restrict__ cur,
                                                        unsigned int* __restrict__ ebuf,
                                                        int E, int EPB, int nbuk) {
    const int e0 = blockIdx.x * EPB;
    const int e1 = min(e0 + EPB, E);
    const int xcd = blockIdx.x & (NXCD - 1);
    for (int e = e0 + threadIdx.x; e < e1; e += 256) {
        int d = dst[e];
        int s = src[e];
        int b = d >> BSH;
        int pos = atomicAdd(&cur[xcd * nbuk + b], 1);
        ebuf[pos] = ((unsigned int)s << BSH) | (unsigned int)(d & 127);
    }
}

// ---- phase D: per-bucket LDS counting sort -> per-node esrc + row_ptr -----
__global__ __launch_bounds__(256) void bucket_sort_k(const unsigned int* __restrict__ ebuf,
                                                     const int* __restrict__ bstart,
                                                     int* __restrict__ row_ptr,
                                                     int* __restrict__ esrc, int n) {
    const int b = blockIdx.x;
    const int beg = bstart[b];
    const int end = bstart[b + 1];
    __shared__ int cnt[128], off[128];
    if (threadIdx.x < 128) cnt[threadIdx.x] = 0;
    __syncthreads();
    for (int i = beg + threadIdx.x; i < end; i += 256)
        atomicAdd(&cnt[ebuf[i] & 127], 1);
    __syncthreads();
    if (threadIdx.x < 128) off[threadIdx.x] = cnt[threadIdx.x];
    __syncthreads();
    for (int d = 1; d < 128; d <<= 1) {
        int t = 0;
        if (threadIdx.x < 128 && threadIdx.x >= d) t = off[threadIdx.x - d];
        __syncthreads();
        if (threadIdx.x < 128) off[threadIdx.x] += t;
        __syncthreads();
    }
    if (threadIdx.x < 128) {
        int ex = off[threadIdx.x] - cnt[threadIdx.x];   // exclusive
        int node = (b << BSH) + threadIdx.x;
        if (node < n) row_ptr[node] = beg + ex;
        cnt[threadIdx.x] = ex;                          // reuse as cursor
    }
    __syncthreads();
    for (int i = beg + threadIdx.x; i < end; i += 256) {
        unsigned int p = ebuf[i];
        int l = (int)(p & 127);
        int pos = beg + atomicAdd(&cnt[l], 1);
        esrc[pos] = (int)(p >> BSH);
    }
}

// ------- GEMM: Hs = f16( (BN(X) @ W) * dis ), chunk-major output ----------
// Hs layout: [NCHUNK][N][32 f16], chunk c holds columns [32c, 32c+32).
template <int OUTD, bool BNIN>
__global__ __launch_bounds__(256) void gemm_k(const float* __restrict__ X,
                                              const float* __restrict__ W,
                                              const float* __restrict__ scale,
                                              const float* __restrict__ shift,
                                              const float* __restrict__ dis,
                                              ushort* __restrict__ Hs, int n) {
    constexpr int K = 128;
    constexpr int ROWS = 32;
    constexpr int CQ = OUTD / 4;      // col quads per row: 32 or 16
    constexpr int TR = 256 / CQ;      // thread groups along rows: 8 or 16
    constexpr int RPT = ROWS / TR;    // rows per thread: 4 or 2

    __shared__ float ws[K * OUTD];
    __shared__ float xs[ROWS][K];

    const int tx = threadIdx.x;

    // stage W
    {
        const float4* W4 = (const float4*)W;
        float4* ws4 = (float4*)ws;
        constexpr int tot = K * OUTD / 4;
        for (int i = tx; i < tot; i += 256) ws4[i] = W4[i];
    }
    // stage X tile (ROWS x K), BN applied on the fly
    const int row0 = blockIdx.x * ROWS;
    {
        const float4* X4 = (const float4*)X;
        constexpr int tot = ROWS * K / 4;  // 1024
        for (int i = tx; i < tot; i += 256) {
            int r = i / (K / 4);
            int kk = i - r * (K / 4);
            int gr = row0 + r;
            float4 v = make_float4(0.f, 0.f, 0.f, 0.f);
            if (gr < n) {
                v = X4[(size_t)gr * (K / 4) + kk];
                if (BNIN) {
                    float4 sc = ((const float4*)scale)[kk];
                    float4 sh = ((const float4*)shift)[kk];
                    v.x = v.x * sc.x + sh.x;
                    v.y = v.y * sc.y + sh.y;
                    v.z = v.z * sc.z + sh.z;
                    v.w = v.w * sc.w + sh.w;
                }
            }
            ((float4*)&xs[r][0])[kk] = v;
        }
    }
    __syncthreads();

    const int cq = tx % CQ;
    const int tr = tx / CQ;

    float acc[RPT][4];
#pragma unroll
    for (int r = 0; r < RPT; ++r)
#pragma unroll
        for (int c = 0; c < 4; ++c) acc[r][c] = 0.f;

#pragma unroll 8
    for (int k = 0; k < K; ++k) {
        float4 wv = ((const float4*)(&ws[k * OUTD]))[cq];
#pragma unroll
        for (int r = 0; r < RPT; ++r) {
            float xv = xs[tr * RPT + r][k];
            acc[r][0] += xv * wv.x;
            acc[r][1] += xv * wv.y;
            acc[r][2] += xv * wv.z;
            acc[r][3] += xv * wv.w;
        }
    }

    const int c = cq >> 3;          // 32-col chunk index
    const int qin = cq & 7;         // quad within chunk
#pragma unroll
    for (int r = 0; r < RPT; ++r) {
        int gr = row0 + tr * RPT + r;
        if (gr < n) {
            float dd = dis[gr];
            ushort4 pk;
            pk.x = f2h(acc[r][0] * dd);
            pk.y = f2h(acc[r][1] * dd);
            pk.z = f2h(acc[r][2] * dd);
            pk.w = f2h(acc[r][3] * dd);
            ((ushort4*)Hs)[((size_t)c * n + gr) * 8 + qin] = pk;
        }
    }
}

// ---------------- chunked gather aggregation (+ fused BN stats) ------------
// Per chunk c (32 cols): O[i][32c..32c+32) = dis[i]*(Hs_c[i] + sum Hs_c[src]) + b
// 2 lanes per 64B row; unroll-4 software pipeline over the edge list.
template <int OUTD, bool STATS>
__global__ __launch_bounds__(256) void gather_k(const ushort* __restrict__ Hs,
                                                const float* __restrict__ dis,
                                                const float* __restrict__ b,
                                                const int* __restrict__ row_ptr,
                                                const int* __restrict__ esrc,
                                                float* __restrict__ O,
                                                float* __restrict__ sums,
                                                float* __restrict__ sumsq, int n) {
    constexpr int NCHUNK = OUTD / 32;   // 4 or 2

    __shared__ float s_sum[32];
    __shared__ float s_sq[32];
    if (STATS) {
        if (threadIdx.x < 32) { s_sum[threadIdx.x] = 0.f; s_sq[threadIdx.x] = 0.f; }
        __syncthreads();
    }

    const int chunk = blockIdx.x & (NCHUNK - 1);
    const int nblk  = blockIdx.x / NCHUNK;
    const int g     = threadIdx.x >> 1;     // node within block: 0..127
    const int lane  = threadIdx.x & 1;      // which half of the 64B row
    const int node  = nblk * 128 + g;

    float acc[16];
#pragma unroll
    for (int c = 0; c < 16; ++c) acc[c] = 0.f;
    float o[16];
#pragma unroll
    for (int c = 0; c < 16; ++c) o[c] = 0.f;

    if (node < n) {
        const uint4* Hc = (const uint4*)Hs + (size_t)chunk * n * 4;  // 4 uint4/node

        {   // self row (dis pre-folded into Hs)
            uint4 v0 = Hc[(size_t)node * 4 + lane];
            uint4 v1 = Hc[(size_t)node * 4 + lane + 2];
            ACC8(0, v0);
            ACC8(8, v1);
        }
        const int beg = row_ptr[node];
        const int end = row_ptr[node + 1];
        int j = beg;
        const int end4 = beg + ((end - beg) & ~3);
        for (; j < end4; j += 4) {
            int s0 = esrc[j + 0];
            int s1 = esrc[j + 1];
            int s2 = esrc[j + 2];
            int s3 = esrc[j + 3];
            uint4 a0 = Hc[(size_t)s0 * 4 + lane];
            uint4 a1 = Hc[(size_t)s1 * 4 + lane];
            uint4 a2 = Hc[(size_t)s2 * 4 + lane];
            uint4 a3 = Hc[(size_t)s3 * 4 + lane];
            uint4 c0 = Hc[(size_t)s0 * 4 + lane + 2];
            uint4 c1 = Hc[(size_t)s1 * 4 + lane + 2];
            uint4 c2 = Hc[(size_t)s2 * 4 + lane + 2];
            uint4 c3 = Hc[(size_t)s3 * 4 + lane + 2];
            ACC8(0, a0); ACC8(8, c0);
            ACC8(0, a1); ACC8(8, c1);
            ACC8(0, a2); ACC8(8, c2);
            ACC8(0, a3); ACC8(8, c3);
        }
        for (; j < end; ++j) {
            int s = esrc[j];
            uint4 a = Hc[(size_t)s * 4 + lane];
            uint4 c = Hc[(size_t)s * 4 + lane + 2];
            ACC8(0, a);
            ACC8(8, c);
        }

        float dd = dis[node];
        const float4* B4 = (const float4*)b + chunk * 8 + lane * 2;
        float4 b0 = B4[0];
        float4 b1 = B4[1];
        float4 b2 = B4[4];
        float4 b3 = B4[5];
        o[0]  = acc[0]  * dd + b0.x;
        o[1]  = acc[1]  * dd + b0.y;
        o[2]  = acc[2]  * dd + b0.z;
        o[3]  = acc[3]  * dd + b0.w;
        o[4]  = acc[4]  * dd + b1.x;
        o[5]  = acc[5]  * dd + b1.y;
        o[6]  = acc[6]  * dd + b1.z;
        o[7]  = acc[7]  * dd + b1.w;
        o[8]  = acc[8]  * dd + b2.x;
        o[9]  = acc[9]  * dd + b2.y;
        o[10] = acc[10] * dd + b2.z;
        o[11] = acc[11] * dd + b2.w;
        o[12] = acc[12] * dd + b3.x;
        o[13] = acc[13] * dd + b3.y;
        o[14] = acc[14] * dd + b3.z;
        o[15] = acc[15] * dd + b3.w;

        float4* O4 = (float4*)O + (size_t)node * (OUTD / 4) + chunk * 8 + lane * 2;
        O4[0] = make_float4(o[0], o[1], o[2], o[3]);
        O4[1] = make_float4(o[4], o[5], o[6], o[7]);
        O4[4] = make_float4(o[8], o[9], o[10], o[11]);
        O4[5] = make_float4(o[12], o[13], o[14], o[15]);
    }

    if (STATS) {
        // lanes of equal parity (lane&1) hold the same 16 columns for 32 nodes
        float sv[16], qv[16];
#pragma unroll
        for (int c = 0; c < 16; ++c) { sv[c] = o[c]; qv[c] = o[c] * o[c]; }
#pragma unroll
        for (int c = 0; c < 16; ++c) {
#pragma unroll
            for (int m = 2; m <= 32; m <<= 1) {
                sv[c] += __shfl_xor(sv[c], m);
                qv[c] += __shfl_xor(qv[c], m);
            }
        }
        if ((threadIdx.x & 63) < 2) {
            // lane 0: cols 0-7 and 16-23 of chunk; lane 1: cols 8-15 and 24-31
            int c0 = lane * 8;
            int c1 = 16 + lane * 8;
#pragma unroll
            for (int c = 0; c < 8; ++c) {
                atomicAdd(&s_sum[c0 + c], sv[c]);
                atomicAdd(&s_sq[c0 + c], qv[c]);
                atomicAdd(&s_sum[c1 + c], sv[8 + c]);
                atomicAdd(&s_sq[c1 + c], qv[8 + c]);
            }
        }
        __syncthreads();
        if (threadIdx.x < 32) {
            atomicAdd(&sums[chunk * 32 + threadIdx.x], s_sum[threadIdx.x]);
            atomicAdd(&sumsq[chunk * 32 + threadIdx.x], s_sq[threadIdx.x]);
        }
    }
}

// ---------------- BN finalize: scale/shift from sums ----------------------
__global__ void bn_finalize_k(const float* __restrict__ sums, const float* __restrict__ sumsq,
                              const float* __restrict__ g, const float* __restrict__ be,
                              float* __restrict__ scale, float* __restrict__ shift, int n) {
    int c = threadIdx.x;  // 128 threads
    float inv_n = 1.0f / (float)n;
    float m = sums[c] * inv_n;
    float v = sumsq[c] * inv_n - m * m;
    float sc = rsqrtf(v + 1e-5f) * g[c];
    scale[c] = sc;
    shift[c] = be[c] - m * sc;
}

// ---------------------------------------------------------------------------
extern "C" void kernel_launch(void* const* d_in, const int* in_sizes, int n_in,
                              void* d_out, int out_size, void* d_ws, size_t ws_size,
                              hipStream_t stream) {
    const float* x   = (const float*)d_in[0];
    const int*   ei  = (const int*)d_in[1];
    const float* W1  = (const float*)d_in[2];
    const float* b1  = (const float*)d_in[3];
    const float* g1  = (const float*)d_in[4];
    const float* be1 = (const float*)d_in[5];
    const float* W2  = (const float*)d_in[6];
    const float* b2  = (const float*)d_in[7];
    const float* g2  = (const float*)d_in[8];
    const float* be2 = (const float*)d_in[9];
    const float* W3  = (const float*)d_in[10];
    const float* b3  = (const float*)d_in[11];
    float* out = (float*)d_out;

    const int N = in_sizes[0] / 128;
    const int E = in_sizes[1] / 2;
    const int* src = ei;
    const int* dst = ei + E;
    const int NBUK = (N + 127) >> BSH;

    // ---- workspace layout ----
    float* wsp   = (float*)d_ws;
    float* dis   = wsp;                               // N f32
    float* stats = wsp + N;                           // 512 f32
    int*   hist   = (int*)(stats + 512);              // NBUK*8
    int*   cur    = hist + NBUK * NXCD;               // NBUK*8
    int*   bstart = cur + NBUK * NXCD;                // NBUK+1
    int*   row_ptr = bstart + NBUK + 1 + 63;          // N+1
    float* bufA  = (float*)(row_ptr + N + 1 + 63);    // N*128 f32 region (Hs f16)
    float* bufB  = bufA + (size_t)N * 128;            // N*128 f32 (agg out)
    unsigned int* ebuf = (unsigned int*)(bufB + (size_t)N * 128);  // E u32
    int*   esrc  = (int*)(ebuf + E);                  // E int

    ushort* Hs = (ushort*)bufA;                       // [NCHUNK][N][32] f16
    int* deg = (int*)bufA;                            // N ints (pre-GEMM only)

    float* sums  = stats;
    float* sumsq = stats + 128;
    float* scale = stats + 256;
    float* shift = stats + 384;

    const int BS = 256;
    dim3 blk(BS);
    const int NB = (N + 255) / 256;
    const int SGRID = 512;                 // count/scatter blocks (multiple of 8)
    const int EPB = (E + SGRID - 1) / SGRID;

    // ---- bucket-sorted CSR build ----
    hipMemsetAsync(deg, 0, (size_t)N * 4, stream);
    hipMemsetAsync(hist, 0, (size_t)NBUK * NXCD * 4, stream);
    count_k<<<dim3(SGRID), blk, 0, stream>>>(dst, hist, deg, E, EPB, NBUK);
    deg_to_dis_k<<<dim3(NB), blk, 0, stream>>>(deg, dis, N);
    scan_hist_k<<<dim3(1), blk, 0, stream>>>(hist, cur, bstart, row_ptr, NBUK, N, E);
    scatter_bucket_k<<<dim3(SGRID), blk, 0, stream>>>(src, dst, cur, ebuf, E, EPB, NBUK);
    bucket_sort_k<<<dim3(NBUK), blk, 0, stream>>>(ebuf, bstart, row_ptr, esrc, N);

    const int gemm_grid = (N + 31) / 32;
    const int NBg = (N + 127) / 128;    // gather node-blocks (128 nodes/block)

    // ---- layer 1 ----
    gemm_k<128, false><<<dim3(gemm_grid), blk, 0, stream>>>(x, W1, nullptr, nullptr, dis, Hs, N);
    hipMemsetAsync(stats, 0, 256 * 4, stream);
    gather_k<128, true><<<dim3(NBg * 4), blk, 0, stream>>>(Hs, dis, b1, row_ptr, esrc,
                                                           bufB, sums, sumsq, N);
    bn_finalize_k<<<dim3(1), dim3(128), 0, stream>>>(sums, sumsq, g1, be1, scale, shift, N);

    // ---- layer 2 (BN applied inside GEMM staging) ----
    gemm_k<128, true><<<dim3(gemm_grid), blk, 0, stream>>>(bufB, W2, scale, shift, dis, Hs, N);
    hipMemsetAsync(stats, 0, 256 * 4, stream);
    gather_k<128, true><<<dim3(NBg * 4), blk, 0, stream>>>(Hs, dis, b2, row_ptr, esrc,
                                                           bufB, sums, sumsq, N);
    bn_finalize_k<<<dim3(1), dim3(128), 0, stream>>>(sums, sumsq, g2, be2, scale, shift, N);

    // ---- layer 3 (OUT = 64, straight to d_out) ----
    gemm_k<64, true><<<dim3(gemm_grid), blk, 0, stream>>>(bufB, W3, scale, shift, dis, Hs, N);
    gather_k<64, false><<<dim3(NBg * 2), blk, 0, stream>>>(Hs, dis, b3, row_ptr, esrc,
                                                           out, nullptr, nullptr, N);
}